// Round 1
// baseline (1979.164 us; speedup 1.0000x reference)
//
#include <hip/hip_runtime.h>
#include <hip/hip_bf16.h>

typedef __bf16 bf16;
typedef __attribute__((ext_vector_type(8))) __bf16 bf16x8;
typedef __attribute__((ext_vector_type(4))) float f32x4;

static __device__ __forceinline__ f32x4 MFMA(bf16x8 a, bf16x8 b, f32x4 c) {
  return __builtin_amdgcn_mfma_f32_16x16x32_bf16(a, b, c, 0, 0, 0);
}

__device__ __forceinline__ float sigm(float x) { return 1.0f / (1.0f + __expf(-x)); }
__device__ __forceinline__ float softplus_(float x) {
  return fmaxf(x, 0.0f) + log1pf(__expf(-fabsf(x)));
}

// ---------------- conversion & init ----------------

__global__ void k_f32_to_bf16(const float* __restrict__ in, bf16* __restrict__ out, int n) {
  for (int i = blockIdx.x * blockDim.x + threadIdx.x; i < n; i += gridDim.x * blockDim.x)
    out[i] = (bf16)in[i];
}

// h0[n] = beliefs[idx_i[n]]  -> bf16, total 6*256*1024
__global__ void k_init_h(const float* __restrict__ beliefs, const int* __restrict__ idx_i,
                         bf16* __restrict__ h) {
  int i = blockIdx.x * blockDim.x + threadIdx.x;  // grid sized exactly
  int n = i >> 18;            // 256*1024 = 2^18
  int rest = i & 262143;
  h[i] = (bf16)beliefs[(size_t)idx_i[n] * 262144 + rest];
}

// ---------------- GRU step ----------------
// hin/hout: (1536,1024) bf16 (rows = n*256+b). Wh: (3*1024,1024), Wi: (3*1024,64),
// actB: (128,256,64) bf16. Computes one full GRU step, writes states when t==K[n][g].
__global__ __launch_bounds__(256) void k_gru_step(
    const bf16* __restrict__ hin, bf16* __restrict__ hout,
    const bf16* __restrict__ Wh, const bf16* __restrict__ Wi,
    const bf16* __restrict__ actB,
    const float* __restrict__ b_ih, const float* __restrict__ b_hh,
    const int* __restrict__ idx_i, const int* __restrict__ Kmat,
    bf16* __restrict__ states, int t) {
  const int m0 = blockIdx.x * 64;   // row tile (within one rollout n: 256/64=4 tiles)
  const int j0 = blockIdx.y * 64;   // h-column tile
  const int tid = threadIdx.x, wave = tid >> 6, lane = tid & 63;

  __shared__ alignas(16) bf16 Al[64][72];      // +8 pad (16B) to break 128B-stride conflicts
  __shared__ alignas(16) bf16 Wl[3][64][72];

  f32x4 accR[4], accZ[4], accN[4], accI[4];
  const f32x4 zero = {0.f, 0.f, 0.f, 0.f};
#pragma unroll
  for (int f = 0; f < 4; ++f) { accR[f] = zero; accZ[f] = zero; accN[f] = zero; accI[f] = zero; }

  const int r = tid >> 3;            // 0..31
  const int c8 = (tid & 7) << 3;     // 0,8,..,56
  const int arow = wave * 16 + (lane & 15);
  const int koff = (lane >> 4) << 3; // 0,8,16,24

  // ---- gh: K=1024 over w_hh ----
  for (int kb = 0; kb < 1024; kb += 64) {
    *(bf16x8*)&Al[r][c8]      = *(const bf16x8*)&hin[(size_t)(m0 + r) * 1024 + kb + c8];
    *(bf16x8*)&Al[r + 32][c8] = *(const bf16x8*)&hin[(size_t)(m0 + r + 32) * 1024 + kb + c8];
#pragma unroll
    for (int g = 0; g < 3; ++g) {
      *(bf16x8*)&Wl[g][r][c8] =
          *(const bf16x8*)&Wh[((size_t)(g * 1024 + j0 + r)) * 1024 + kb + c8];
      *(bf16x8*)&Wl[g][r + 32][c8] =
          *(const bf16x8*)&Wh[((size_t)(g * 1024 + j0 + r + 32)) * 1024 + kb + c8];
    }
    __syncthreads();
#pragma unroll
    for (int kk = 0; kk < 64; kk += 32) {
      bf16x8 av = *(const bf16x8*)&Al[arow][kk + koff];
#pragma unroll
      for (int nf = 0; nf < 4; ++nf) {
        int wr = nf * 16 + (lane & 15);
        accR[nf] = MFMA(av, *(const bf16x8*)&Wl[0][wr][kk + koff], accR[nf]);
        accZ[nf] = MFMA(av, *(const bf16x8*)&Wl[1][wr][kk + koff], accZ[nf]);
        accN[nf] = MFMA(av, *(const bf16x8*)&Wl[2][wr][kk + koff], accN[nf]);
      }
    }
    __syncthreads();
  }

  // ---- gi: K=64 over w_ih, A = actions[idx_i[n]+t] ----
  const int n = m0 >> 8;
  const int i_n = idx_i[n];
  const int b0 = m0 & 255;
  {
    const size_t abase = ((size_t)(i_n + t) * 256) * 64;
    *(bf16x8*)&Al[r][c8]      = *(const bf16x8*)&actB[abase + (size_t)(b0 + r) * 64 + c8];
    *(bf16x8*)&Al[r + 32][c8] = *(const bf16x8*)&actB[abase + (size_t)(b0 + r + 32) * 64 + c8];
#pragma unroll
    for (int g = 0; g < 3; ++g) {
      *(bf16x8*)&Wl[g][r][c8] = *(const bf16x8*)&Wi[((size_t)(g * 1024 + j0 + r)) * 64 + c8];
      *(bf16x8*)&Wl[g][r + 32][c8] =
          *(const bf16x8*)&Wi[((size_t)(g * 1024 + j0 + r + 32)) * 64 + c8];
    }
    __syncthreads();
#pragma unroll
    for (int kk = 0; kk < 64; kk += 32) {
      bf16x8 av = *(const bf16x8*)&Al[arow][kk + koff];
#pragma unroll
      for (int nf = 0; nf < 4; ++nf) {
        int wr = nf * 16 + (lane & 15);
        accR[nf] = MFMA(av, *(const bf16x8*)&Wl[0][wr][kk + koff], accR[nf]);
        accZ[nf] = MFMA(av, *(const bf16x8*)&Wl[1][wr][kk + koff], accZ[nf]);
        accI[nf] = MFMA(av, *(const bf16x8*)&Wl[2][wr][kk + koff], accI[nf]);
      }
    }
  }

  // ---- epilogue: gates + state update ----
  const int k0 = Kmat[n * 4 + 0], k1 = Kmat[n * 4 + 1];
  const int k2 = Kmat[n * 4 + 2], k3 = Kmat[n * 4 + 3];
#pragma unroll
  for (int nf = 0; nf < 4; ++nf) {
    int j = j0 + nf * 16 + (lane & 15);
    float br = b_ih[j] + b_hh[j];
    float bz = b_ih[1024 + j] + b_hh[1024 + j];
    float bin = b_ih[2048 + j];
    float bhn = b_hh[2048 + j];
#pragma unroll
    for (int i = 0; i < 4; ++i) {
      int m = m0 + wave * 16 + ((lane >> 4) << 2) + i;
      float rg = sigm(accR[nf][i] + br);
      float zg = sigm(accZ[nf][i] + bz);
      float ng = tanhf(accI[nf][i] + bin + rg * (accN[nf][i] + bhn));
      float hprev = (float)hin[(size_t)m * 1024 + j];
      float hnew = (1.0f - zg) * ng + zg * hprev;
      bf16 hb = (bf16)hnew;
      hout[(size_t)m * 1024 + j] = hb;
      int b = m & 255;
      if (k0 == t) states[((size_t)(n * 4 + 0) * 256 + b) * 1024 + j] = hb;
      if (k1 == t) states[((size_t)(n * 4 + 1) * 256 + b) * 1024 + j] = hb;
      if (k2 == t) states[((size_t)(n * 4 + 2) * 256 + b) * 1024 + j] = hb;
      if (k3 == t) states[((size_t)(n * 4 + 3) * 256 + b) * 1024 + j] = hb;
    }
  }
}

// ---------------- generic GEMM: C = A(M x K) @ W(N x K)^T, fused epilogues ----------------
// EPI 0: relu(+bias) -> bf16 out            (mlp1)
// EPI 1: relu(+bias) + resid -> bf16 out    (mlp2, residual add)
// EPI 2: +bias -> f32 out, mask j<Nreal     (logits)
template <int EPI>
__global__ __launch_bounds__(256) void k_gemm_epi(
    const bf16* __restrict__ A, const bf16* __restrict__ W, int K, int Nreal, int ld_out,
    const float* __restrict__ bias, const bf16* __restrict__ resid,
    float* __restrict__ outF, bf16* __restrict__ outB) {
  const int m0 = blockIdx.x * 64;
  const int j0 = blockIdx.y * 64;
  const int tid = threadIdx.x, wave = tid >> 6, lane = tid & 63;
  __shared__ alignas(16) bf16 Al[64][72];
  __shared__ alignas(16) bf16 Wl[64][72];

  f32x4 acc[4];
  const f32x4 zero = {0.f, 0.f, 0.f, 0.f};
#pragma unroll
  for (int f = 0; f < 4; ++f) acc[f] = zero;

  const int r = tid >> 3, c8 = (tid & 7) << 3;
  const int arow = wave * 16 + (lane & 15);
  const int koff = (lane >> 4) << 3;

  for (int kb = 0; kb < K; kb += 64) {
    *(bf16x8*)&Al[r][c8]      = *(const bf16x8*)&A[(size_t)(m0 + r) * K + kb + c8];
    *(bf16x8*)&Al[r + 32][c8] = *(const bf16x8*)&A[(size_t)(m0 + r + 32) * K + kb + c8];
    int jr = j0 + r;      if (jr >= Nreal) jr = Nreal - 1;
    int jr2 = j0 + r + 32; if (jr2 >= Nreal) jr2 = Nreal - 1;
    *(bf16x8*)&Wl[r][c8]      = *(const bf16x8*)&W[(size_t)jr * K + kb + c8];
    *(bf16x8*)&Wl[r + 32][c8] = *(const bf16x8*)&W[(size_t)jr2 * K + kb + c8];
    __syncthreads();
#pragma unroll
    for (int kk = 0; kk < 64; kk += 32) {
      bf16x8 av = *(const bf16x8*)&Al[arow][kk + koff];
#pragma unroll
      for (int nf = 0; nf < 4; ++nf) {
        acc[nf] = MFMA(av, *(const bf16x8*)&Wl[nf * 16 + (lane & 15)][kk + koff], acc[nf]);
      }
    }
    __syncthreads();
  }

#pragma unroll
  for (int nf = 0; nf < 4; ++nf) {
    int j = j0 + nf * 16 + (lane & 15);
    float bj = (j < Nreal) ? bias[j] : 0.f;
#pragma unroll
    for (int i = 0; i < 4; ++i) {
      int m = m0 + wave * 16 + ((lane >> 4) << 2) + i;
      float v = acc[nf][i] + bj;
      if (EPI == 0) {
        outB[(size_t)m * ld_out + j] = (bf16)fmaxf(v, 0.f);
      } else if (EPI == 1) {
        v = fmaxf(v, 0.f) + (float)resid[(size_t)m * ld_out + j];
        outB[(size_t)m * ld_out + j] = (bf16)v;
      } else {
        if (j < Nreal) outF[(size_t)m * ld_out + j] = v;
      }
    }
  }
}

// ---------------- loss ----------------
// One block per row (n,g,b). logits row: 814 f32 (agent 0..406, opp 407..813).
__global__ __launch_bounds__(256) void k_loss_rows(
    const float* __restrict__ logits, const float* __restrict__ obs,
    const int* __restrict__ idx_i, const int* __restrict__ Kmat,
    float* __restrict__ partials) {
  const int row = blockIdx.x;
  const int n = row >> 10, g = (row >> 8) & 3, b = row & 255;
  const int i = idx_i[n], k = Kmat[n * 4 + g];
  const float* L = logits + (size_t)row * 814;
  const float* ob = obs + ((size_t)(k + i + 1) * 256 + b) * 16;
  const int tid = threadIdx.x, lane = tid & 63, wv = tid >> 6;
  __shared__ float red[4];

  float total = 0.f;
#pragma unroll
  for (int p = 0; p < 2; ++p) {
    const float* Lp = L + p * 407;
    const float* tg = ob + p * 8;
    // max over 400 logits
    float mx = -1e30f;
    for (int c = tid; c < 400; c += 256) mx = fmaxf(mx, Lp[c]);
#pragma unroll
    for (int s = 32; s; s >>= 1) mx = fmaxf(mx, __shfl_xor(mx, s));
    __syncthreads();
    if (lane == 0) red[wv] = mx;
    __syncthreads();
    mx = fmaxf(fmaxf(red[0], red[1]), fmaxf(red[2], red[3]));
    __syncthreads();
    // sum exp
    float se = 0.f;
    for (int c = tid; c < 400; c += 256) se += __expf(Lp[c] - mx);
#pragma unroll
    for (int s = 32; s; s >>= 1) se += __shfl_xor(se, s);
    if (lane == 0) red[wv] = se;
    __syncthreads();
    se = red[0] + red[1] + red[2] + red[3];
    __syncthreads();

    if (tid == 0) {
      int cls = (int)tg[0];
      float lse = mx + logf(se);
      float v = lse - Lp[cls];                       // ce
      float d0 = Lp[400] - tg[1], d1 = Lp[401] - tg[2];
      v += 0.5f * (d0 * d0 + d1 * d1);
      float s2 = softplus_(Lp[402]) - tg[3]; v += s2 * s2;
      float s3 = softplus_(Lp[403]) - tg[4]; v += s3 * s3;
      v += softplus_(Lp[404]) - Lp[404] * tg[5];
      v += softplus_(Lp[405]) - Lp[405] * tg[6];
      v += softplus_(Lp[406]) - Lp[406] * tg[7];
      total += v;
    }
    __syncthreads();
  }
  if (tid == 0) partials[row] = total * (1.0f / 1024.0f);
}

__global__ void k_reduce_final(const float* __restrict__ partials, float* __restrict__ out) {
  __shared__ float s[256];
  float v = 0.f;
  for (int i = threadIdx.x; i < 6144; i += 256) v += partials[i];
  s[threadIdx.x] = v;
  __syncthreads();
  for (int st = 128; st; st >>= 1) {
    if (threadIdx.x < st) s[threadIdx.x] += s[threadIdx.x + st];
    __syncthreads();
  }
  if (threadIdx.x == 0) out[0] = s[0];
}

// ---------------- launcher ----------------

extern "C" void kernel_launch(void* const* d_in, const int* in_sizes, int n_in,
                              void* d_out, int out_size, void* d_ws, size_t ws_size,
                              hipStream_t stream) {
  const float* obs      = (const float*)d_in[0];   // (128,256,16)
  const float* actions  = (const float*)d_in[1];   // (128,256,64)
  const float* beliefs  = (const float*)d_in[2];   // (128,256,1024)
  const float* w_ih     = (const float*)d_in[3];   // (3072,64)
  const float* w_hh     = (const float*)d_in[4];   // (3072,1024)
  const float* b_ih     = (const float*)d_in[5];
  const float* b_hh     = (const float*)d_in[6];
  const float* pre_w1   = (const float*)d_in[7];   // (64,1024)
  const float* pre_b1   = (const float*)d_in[8];
  const float* pre_w2   = (const float*)d_in[9];   // (1024,64)
  const float* pre_b2   = (const float*)d_in[10];
  const float* dec_w    = (const float*)d_in[11];  // (814,1024)
  const float* dec_b    = (const float*)d_in[12];
  const int*   idx_i    = (const int*)d_in[13];    // (6,)
  const int*   Kmat     = (const int*)d_in[14];    // (6,4)
  float* outF = (float*)d_out;

  // workspace carve (all 256B aligned)
  char* p = (char*)d_ws;
  auto carve = [&](size_t bytes) {
    char* q = p;
    p += (bytes + 255) & ~(size_t)255;
    return q;
  };
  bf16* Wh      = (bf16*)carve(3072u * 1024u * 2u);
  bf16* Wi      = (bf16*)carve(3072u * 64u * 2u);
  bf16* actB    = (bf16*)carve(128u * 256u * 64u * 2u);
  bf16* preW1b  = (bf16*)carve(64u * 1024u * 2u);
  bf16* preW2b  = (bf16*)carve(1024u * 64u * 2u);
  bf16* decWb   = (bf16*)carve(814u * 1024u * 2u);
  bf16* hA      = (bf16*)carve(1536u * 1024u * 2u);
  bf16* hB      = (bf16*)carve(1536u * 1024u * 2u);
  bf16* states  = (bf16*)carve(6144u * 1024u * 2u);
  bf16* h1      = (bf16*)carve(6144u * 64u * 2u);
  bf16* xbuf    = (bf16*)carve(6144u * 1024u * 2u);
  float* logits = (float*)carve((size_t)6144u * 814u * 4u);
  float* partials = (float*)carve(6144u * 4u);

  // weight / activation conversions
  auto cvt = [&](const float* src, bf16* dst, int n) {
    int grid = (n + 255) / 256;
    if (grid > 4096) grid = 4096;
    k_f32_to_bf16<<<grid, 256, 0, stream>>>(src, dst, n);
  };
  cvt(w_hh, Wh, 3072 * 1024);
  cvt(w_ih, Wi, 3072 * 64);
  cvt(actions, actB, 128 * 256 * 64);
  cvt(pre_w1, preW1b, 64 * 1024);
  cvt(pre_w2, preW2b, 1024 * 64);
  cvt(dec_w, decWb, 814 * 1024);

  k_init_h<<<6144, 256, 0, stream>>>(beliefs, idx_i, hA);

  // 30 sequential GRU steps, ping-pong h buffers
  for (int t = 0; t < 30; ++t) {
    const bf16* hi = (t & 1) ? hB : hA;
    bf16* ho = (t & 1) ? hA : hB;
    k_gru_step<<<dim3(24, 16), 256, 0, stream>>>(hi, ho, Wh, Wi, actB, b_ih, b_hh,
                                                 idx_i, Kmat, states, t);
  }

  // decoder: mlp1 -> mlp2+residual -> logits
  k_gemm_epi<0><<<dim3(96, 1), 256, 0, stream>>>(states, preW1b, 1024, 64, 64,
                                                 pre_b1, nullptr, nullptr, h1);
  k_gemm_epi<1><<<dim3(96, 16), 256, 0, stream>>>(h1, preW2b, 64, 1024, 1024,
                                                  pre_b2, states, nullptr, xbuf);
  k_gemm_epi<2><<<dim3(96, 13), 256, 0, stream>>>(xbuf, decWb, 1024, 814, 814,
                                                  dec_b, nullptr, logits, nullptr);

  // loss
  k_loss_rows<<<6144, 256, 0, stream>>>(logits, obs, idx_i, Kmat, partials);
  k_reduce_final<<<1, 256, 0, stream>>>(partials, outF);
}

// Round 2
// 799.004 us; speedup vs baseline: 2.4770x; 2.4770x over previous
//
#include <hip/hip_runtime.h>
#include <hip/hip_bf16.h>

typedef __bf16 bf16;
typedef __attribute__((ext_vector_type(8))) __bf16 bf16x8;
typedef __attribute__((ext_vector_type(4))) float f32x4;

static __device__ __forceinline__ f32x4 MFMA(bf16x8 a, bf16x8 b, f32x4 c) {
  return __builtin_amdgcn_mfma_f32_16x16x32_bf16(a, b, c, 0, 0, 0);
}

__device__ __forceinline__ float sigm(float x) { return 1.0f / (1.0f + __expf(-x)); }
__device__ __forceinline__ float softplus_(float x) {
  return fmaxf(x, 0.0f) + log1pf(__expf(-fabsf(x)));
}

// async global->LDS, 16B per lane. lds ptr must be wave-uniform base (+lane*16 implicit).
__device__ __forceinline__ void gl16(const bf16* g, char* l) {
  __builtin_amdgcn_global_load_lds(
      (const __attribute__((address_space(1))) char*)g,
      (__attribute__((address_space(3))) char*)l, 16, 0, 0);
}

// ---------------- conversion & init ----------------

__global__ void k_f32_to_bf16(const float* __restrict__ in, bf16* __restrict__ out, int n) {
  for (int i = blockIdx.x * blockDim.x + threadIdx.x; i < n; i += gridDim.x * blockDim.x)
    out[i] = (bf16)in[i];
}

__global__ void k_init_h(const float* __restrict__ beliefs, const int* __restrict__ idx_i,
                         bf16* __restrict__ h) {
  int i = blockIdx.x * blockDim.x + threadIdx.x;
  int n = i >> 18;
  int rest = i & 262143;
  h[i] = (bf16)beliefs[(size_t)idx_i[n] * 262144 + rest];
}

// ---------------- GRU step (rewritten) ----------------
// Block tile: 128 rows x (32 j-cols x 3 gates). Grid 384 (12 m-tiles x 32 j-tiles),
// XCD-remapped so each XCD owns 4 j-tiles (Wh slice 768KB -> L2-resident).
// Double-buffered global_load_lds staging with counted vmcnt(7); LDS XOR-swizzle
// (pre-swizzled source, swizzled read; linear dest as global_load_lds requires).
__global__ __launch_bounds__(256, 2) void k_gru_step(
    const bf16* __restrict__ hin, bf16* __restrict__ hout,
    const bf16* __restrict__ Wh, const bf16* __restrict__ Wi,
    const bf16* __restrict__ actB,
    const float* __restrict__ b_ih, const float* __restrict__ b_hh,
    const int* __restrict__ idx_i, const int* __restrict__ Kmat,
    bf16* __restrict__ states, int step) {
  // --- XCD-aware decode: pid%8 = XCD; XCD k owns j-tiles 4k..4k+3 ---
  const int pid = blockIdx.x;
  const int xcd = pid & 7;
  const int q = pid >> 3;            // 0..47
  const int mt = q % 12;
  const int jhi = q / 12;            // 0..3
  const int m0 = mt * 128;
  const int j0 = (xcd * 4 + jhi) * 32;

  const int tid = threadIdx.x, wave = tid >> 6, lane = tid & 63;
  const int ln8 = lane >> 3;                         // 0..7
  const int colE = (((lane & 7) ^ ln8) << 3);        // pre-swizzled source col (elements)
  const int l15 = lane & 15;
  const int sw = (lane & 7) << 4;                    // read-side XOR (bytes)
  const int kgrp = (lane >> 4) << 3;                 // 0,8,16,24

  // LDS: linear [row][64] bf16 (128B rows), content column-swizzled by (row&7)<<4 bytes.
  __shared__ alignas(16) bf16 As[2][128][64];        // 2 x 16KB
  __shared__ alignas(16) bf16 Ws[2][96][64];         // 2 x 12KB (rows = g*32 + jr)

  const int n = m0 >> 8;
  const int i_n = idx_i[n];
  const bf16* act0 = actB + ((size_t)(i_n + step) * 256 + (m0 & 255)) * 64;

  // precomputed per-thread global bases (element offsets incl. swizzled col)
  const bf16* aB[4];
  const bf16* wB[3];
#pragma unroll
  for (int i = 0; i < 4; ++i)
    aB[i] = hin + (size_t)(m0 + i * 32 + wave * 8 + ln8) * 1024 + colE;
#pragma unroll
  for (int i = 0; i < 3; ++i) {
    int wr = i * 32 + wave * 8 + ln8;                // 0..95
    wB[i] = Wh + ((size_t)((wr >> 5) * 1024 + j0 + (wr & 31))) * 1024 + colE;
  }

  auto stage = [&](int buf, int it) {
    char* adst = (char*)As + buf * 16384 + wave * 1024;
    char* wdst = (char*)Ws + buf * 12288 + wave * 1024;
    if (it < 16) {
      const int kb = it * 64;
#pragma unroll
      for (int i = 0; i < 4; ++i) gl16(aB[i] + kb, adst + i * 4096);
#pragma unroll
      for (int i = 0; i < 3; ++i) gl16(wB[i] + kb, wdst + i * 4096);
    } else {  // gi: A = actions tile, W = Wi (both 64-wide rows)
#pragma unroll
      for (int i = 0; i < 4; ++i)
        gl16(act0 + (size_t)(i * 32 + wave * 8 + ln8) * 64 + colE, adst + i * 4096);
#pragma unroll
      for (int i = 0; i < 3; ++i) {
        int wr = i * 32 + wave * 8 + ln8;
        gl16(Wi + (size_t)((wr >> 5) * 1024 + j0 + (wr & 31)) * 64 + colE, wdst + i * 4096);
      }
    }
  };

  f32x4 aRZ[2][2][2];   // [i-frag][gate r/z][jf]
  f32x4 aHN[2][2];      // gate n, h-part
  f32x4 aIN[2][2];      // gate n, input-part
  const f32x4 zero = {0.f, 0.f, 0.f, 0.f};
#pragma unroll
  for (int i = 0; i < 2; ++i)
#pragma unroll
    for (int jf = 0; jf < 2; ++jf) {
      aRZ[i][0][jf] = zero; aRZ[i][1][jf] = zero; aHN[i][jf] = zero; aIN[i][jf] = zero;
    }

  stage(0, 0);  // prologue

  for (int t = 0; t < 17; ++t) {
    if (t < 16) {
      stage((t + 1) & 1, t + 1);
      asm volatile("s_waitcnt vmcnt(7)" ::: "memory");   // current buffer's 7 loads done
    } else {
      asm volatile("s_waitcnt vmcnt(0)" ::: "memory");
    }
    __builtin_amdgcn_s_barrier();

    const char* ab = (const char*)As + (t & 1) * 16384;
    const char* wb = (const char*)Ws + (t & 1) * 12288;
    f32x4 (*acc2)[2] = (t == 16) ? aIN : aHN;
#pragma unroll
    for (int kk = 0; kk < 64; kk += 32) {
      const int kbyte = ((kk + kgrp) * 2) ^ sw;
      bf16x8 a0 = *(const bf16x8*)(ab + (wave * 32 + l15) * 128 + kbyte);
      bf16x8 a1 = *(const bf16x8*)(ab + (wave * 32 + 16 + l15) * 128 + kbyte);
      bf16x8 b0 = *(const bf16x8*)(wb + (0 * 16 + l15) * 128 + kbyte);
      bf16x8 b1 = *(const bf16x8*)(wb + (1 * 16 + l15) * 128 + kbyte);
      bf16x8 b2 = *(const bf16x8*)(wb + (2 * 16 + l15) * 128 + kbyte);
      bf16x8 b3 = *(const bf16x8*)(wb + (3 * 16 + l15) * 128 + kbyte);
      bf16x8 b4 = *(const bf16x8*)(wb + (4 * 16 + l15) * 128 + kbyte);
      bf16x8 b5 = *(const bf16x8*)(wb + (5 * 16 + l15) * 128 + kbyte);
      aRZ[0][0][0] = MFMA(a0, b0, aRZ[0][0][0]);
      aRZ[1][0][0] = MFMA(a1, b0, aRZ[1][0][0]);
      aRZ[0][0][1] = MFMA(a0, b1, aRZ[0][0][1]);
      aRZ[1][0][1] = MFMA(a1, b1, aRZ[1][0][1]);
      aRZ[0][1][0] = MFMA(a0, b2, aRZ[0][1][0]);
      aRZ[1][1][0] = MFMA(a1, b2, aRZ[1][1][0]);
      aRZ[0][1][1] = MFMA(a0, b3, aRZ[0][1][1]);
      aRZ[1][1][1] = MFMA(a1, b3, aRZ[1][1][1]);
      acc2[0][0] = MFMA(a0, b4, acc2[0][0]);
      acc2[1][0] = MFMA(a1, b4, acc2[1][0]);
      acc2[0][1] = MFMA(a0, b5, acc2[0][1]);
      acc2[1][1] = MFMA(a1, b5, acc2[1][1]);
    }
    __builtin_amdgcn_sched_barrier(0);   // pin reads+MFMAs before barrier (no DS in flight)
    __builtin_amdgcn_s_barrier();
  }

  // ---- epilogue: gates + state update ----
  const int k0 = Kmat[n * 4 + 0], k1 = Kmat[n * 4 + 1];
  const int k2 = Kmat[n * 4 + 2], k3 = Kmat[n * 4 + 3];
#pragma unroll
  for (int i = 0; i < 2; ++i) {
#pragma unroll
    for (int jf = 0; jf < 2; ++jf) {
      const int j = j0 + jf * 16 + l15;
      const float br = b_ih[j] + b_hh[j];
      const float bz = b_ih[1024 + j] + b_hh[1024 + j];
      const float bin = b_ih[2048 + j];
      const float bhn = b_hh[2048 + j];
#pragma unroll
      for (int ii = 0; ii < 4; ++ii) {
        const int m = m0 + wave * 32 + i * 16 + ((lane >> 4) << 2) + ii;
        float rg = sigm(aRZ[i][0][jf][ii] + br);
        float zg = sigm(aRZ[i][1][jf][ii] + bz);
        float ng = tanhf(aIN[i][jf][ii] + bin + rg * (aHN[i][jf][ii] + bhn));
        float hp = (float)hin[(size_t)m * 1024 + j];
        float hnew = (1.0f - zg) * ng + zg * hp;
        bf16 hb = (bf16)hnew;
        hout[(size_t)m * 1024 + j] = hb;
        const int b = m & 255;
        if (k0 == step) states[((size_t)(n * 4 + 0) * 256 + b) * 1024 + j] = hb;
        if (k1 == step) states[((size_t)(n * 4 + 1) * 256 + b) * 1024 + j] = hb;
        if (k2 == step) states[((size_t)(n * 4 + 2) * 256 + b) * 1024 + j] = hb;
        if (k3 == step) states[((size_t)(n * 4 + 3) * 256 + b) * 1024 + j] = hb;
      }
    }
  }
}

// ---------------- generic GEMM: C = A(M x K) @ W(N x K)^T, fused epilogues ----------------
template <int EPI>
__global__ __launch_bounds__(256) void k_gemm_epi(
    const bf16* __restrict__ A, const bf16* __restrict__ W, int K, int Nreal, int ld_out,
    const float* __restrict__ bias, const bf16* __restrict__ resid,
    float* __restrict__ outF, bf16* __restrict__ outB) {
  const int m0 = blockIdx.x * 64;
  const int j0 = blockIdx.y * 64;
  const int tid = threadIdx.x, wave = tid >> 6, lane = tid & 63;
  __shared__ alignas(16) bf16 Al[64][72];
  __shared__ alignas(16) bf16 Wl[64][72];

  f32x4 acc[4];
  const f32x4 zero = {0.f, 0.f, 0.f, 0.f};
#pragma unroll
  for (int f = 0; f < 4; ++f) acc[f] = zero;

  const int r = tid >> 3, c8 = (tid & 7) << 3;
  const int arow = wave * 16 + (lane & 15);
  const int koff = (lane >> 4) << 3;

  for (int kb = 0; kb < K; kb += 64) {
    *(bf16x8*)&Al[r][c8]      = *(const bf16x8*)&A[(size_t)(m0 + r) * K + kb + c8];
    *(bf16x8*)&Al[r + 32][c8] = *(const bf16x8*)&A[(size_t)(m0 + r + 32) * K + kb + c8];
    int jr = j0 + r;      if (jr >= Nreal) jr = Nreal - 1;
    int jr2 = j0 + r + 32; if (jr2 >= Nreal) jr2 = Nreal - 1;
    *(bf16x8*)&Wl[r][c8]      = *(const bf16x8*)&W[(size_t)jr * K + kb + c8];
    *(bf16x8*)&Wl[r + 32][c8] = *(const bf16x8*)&W[(size_t)jr2 * K + kb + c8];
    __syncthreads();
#pragma unroll
    for (int kk = 0; kk < 64; kk += 32) {
      bf16x8 av = *(const bf16x8*)&Al[arow][kk + koff];
#pragma unroll
      for (int nf = 0; nf < 4; ++nf) {
        acc[nf] = MFMA(av, *(const bf16x8*)&Wl[nf * 16 + (lane & 15)][kk + koff], acc[nf]);
      }
    }
    __syncthreads();
  }

#pragma unroll
  for (int nf = 0; nf < 4; ++nf) {
    int j = j0 + nf * 16 + (lane & 15);
    float bj = (j < Nreal) ? bias[j] : 0.f;
#pragma unroll
    for (int i = 0; i < 4; ++i) {
      int m = m0 + wave * 16 + ((lane >> 4) << 2) + i;
      float v = acc[nf][i] + bj;
      if (EPI == 0) {
        outB[(size_t)m * ld_out + j] = (bf16)fmaxf(v, 0.f);
      } else if (EPI == 1) {
        v = fmaxf(v, 0.f) + (float)resid[(size_t)m * ld_out + j];
        outB[(size_t)m * ld_out + j] = (bf16)v;
      } else {
        if (j < Nreal) outF[(size_t)m * ld_out + j] = v;
      }
    }
  }
}

// ---------------- loss ----------------
__global__ __launch_bounds__(256) void k_loss_rows(
    const float* __restrict__ logits, const float* __restrict__ obs,
    const int* __restrict__ idx_i, const int* __restrict__ Kmat,
    float* __restrict__ partials) {
  const int row = blockIdx.x;
  const int n = row >> 10, g = (row >> 8) & 3, b = row & 255;
  const int i = idx_i[n], k = Kmat[n * 4 + g];
  const float* L = logits + (size_t)row * 814;
  const float* ob = obs + ((size_t)(k + i + 1) * 256 + b) * 16;
  const int tid = threadIdx.x, lane = tid & 63, wv = tid >> 6;
  __shared__ float red[4];

  float total = 0.f;
#pragma unroll
  for (int p = 0; p < 2; ++p) {
    const float* Lp = L + p * 407;
    const float* tg = ob + p * 8;
    float mx = -1e30f;
    for (int c = tid; c < 400; c += 256) mx = fmaxf(mx, Lp[c]);
#pragma unroll
    for (int s = 32; s; s >>= 1) mx = fmaxf(mx, __shfl_xor(mx, s));
    __syncthreads();
    if (lane == 0) red[wv] = mx;
    __syncthreads();
    mx = fmaxf(fmaxf(red[0], red[1]), fmaxf(red[2], red[3]));
    __syncthreads();
    float se = 0.f;
    for (int c = tid; c < 400; c += 256) se += __expf(Lp[c] - mx);
#pragma unroll
    for (int s = 32; s; s >>= 1) se += __shfl_xor(se, s);
    if (lane == 0) red[wv] = se;
    __syncthreads();
    se = red[0] + red[1] + red[2] + red[3];
    __syncthreads();

    if (tid == 0) {
      int cls = (int)tg[0];
      float lse = mx + logf(se);
      float v = lse - Lp[cls];
      float d0 = Lp[400] - tg[1], d1 = Lp[401] - tg[2];
      v += 0.5f * (d0 * d0 + d1 * d1);
      float s2 = softplus_(Lp[402]) - tg[3]; v += s2 * s2;
      float s3 = softplus_(Lp[403]) - tg[4]; v += s3 * s3;
      v += softplus_(Lp[404]) - Lp[404] * tg[5];
      v += softplus_(Lp[405]) - Lp[405] * tg[6];
      v += softplus_(Lp[406]) - Lp[406] * tg[7];
      total += v;
    }
    __syncthreads();
  }
  if (tid == 0) partials[row] = total * (1.0f / 1024.0f);
}

__global__ void k_reduce_final(const float* __restrict__ partials, float* __restrict__ out) {
  __shared__ float s[256];
  float v = 0.f;
  for (int i = threadIdx.x; i < 6144; i += 256) v += partials[i];
  s[threadIdx.x] = v;
  __syncthreads();
  for (int st = 128; st; st >>= 1) {
    if (threadIdx.x < st) s[threadIdx.x] += s[threadIdx.x + st];
    __syncthreads();
  }
  if (threadIdx.x == 0) out[0] = s[0];
}

// ---------------- launcher ----------------

extern "C" void kernel_launch(void* const* d_in, const int* in_sizes, int n_in,
                              void* d_out, int out_size, void* d_ws, size_t ws_size,
                              hipStream_t stream) {
  const float* obs      = (const float*)d_in[0];
  const float* actions  = (const float*)d_in[1];
  const float* beliefs  = (const float*)d_in[2];
  const float* w_ih     = (const float*)d_in[3];
  const float* w_hh     = (const float*)d_in[4];
  const float* b_ih     = (const float*)d_in[5];
  const float* b_hh     = (const float*)d_in[6];
  const float* pre_w1   = (const float*)d_in[7];
  const float* pre_b1   = (const float*)d_in[8];
  const float* pre_w2   = (const float*)d_in[9];
  const float* pre_b2   = (const float*)d_in[10];
  const float* dec_w    = (const float*)d_in[11];
  const float* dec_b    = (const float*)d_in[12];
  const int*   idx_i    = (const int*)d_in[13];
  const int*   Kmat     = (const int*)d_in[14];
  float* outF = (float*)d_out;

  char* p = (char*)d_ws;
  auto carve = [&](size_t bytes) {
    char* q = p;
    p += (bytes + 255) & ~(size_t)255;
    return q;
  };
  bf16* Wh      = (bf16*)carve(3072u * 1024u * 2u);
  bf16* Wi      = (bf16*)carve(3072u * 64u * 2u);
  bf16* actB    = (bf16*)carve(128u * 256u * 64u * 2u);
  bf16* preW1b  = (bf16*)carve(64u * 1024u * 2u);
  bf16* preW2b  = (bf16*)carve(1024u * 64u * 2u);
  bf16* decWb   = (bf16*)carve(814u * 1024u * 2u);
  bf16* hA      = (bf16*)carve(1536u * 1024u * 2u);
  bf16* hB      = (bf16*)carve(1536u * 1024u * 2u);
  bf16* states  = (bf16*)carve(6144u * 1024u * 2u);
  bf16* h1      = (bf16*)carve(6144u * 64u * 2u);
  bf16* xbuf    = (bf16*)carve(6144u * 1024u * 2u);
  float* logits = (float*)carve((size_t)6144u * 814u * 4u);
  float* partials = (float*)carve(6144u * 4u);

  auto cvt = [&](const float* src, bf16* dst, int n) {
    int grid = (n + 255) / 256;
    if (grid > 4096) grid = 4096;
    k_f32_to_bf16<<<grid, 256, 0, stream>>>(src, dst, n);
  };
  cvt(w_hh, Wh, 3072 * 1024);
  cvt(w_ih, Wi, 3072 * 64);
  cvt(actions, actB, 128 * 256 * 64);
  cvt(pre_w1, preW1b, 64 * 1024);
  cvt(pre_w2, preW2b, 1024 * 64);
  cvt(dec_w, decWb, 814 * 1024);

  k_init_h<<<6144, 256, 0, stream>>>(beliefs, idx_i, hA);

  for (int t = 0; t < 30; ++t) {
    const bf16* hi = (t & 1) ? hB : hA;
    bf16* ho = (t & 1) ? hA : hB;
    k_gru_step<<<384, 256, 0, stream>>>(hi, ho, Wh, Wi, actB, b_ih, b_hh,
                                        idx_i, Kmat, states, t);
  }

  k_gemm_epi<0><<<dim3(96, 1), 256, 0, stream>>>(states, preW1b, 1024, 64, 64,
                                                 pre_b1, nullptr, nullptr, h1);
  k_gemm_epi<1><<<dim3(96, 16), 256, 0, stream>>>(h1, preW2b, 64, 1024, 1024,
                                                  pre_b2, states, nullptr, xbuf);
  k_gemm_epi<2><<<dim3(96, 13), 256, 0, stream>>>(xbuf, decWb, 1024, 814, 814,
                                                  dec_b, nullptr, logits, nullptr);

  k_loss_rows<<<6144, 256, 0, stream>>>(logits, obs, idx_i, Kmat, partials);
  k_reduce_final<<<1, 256, 0, stream>>>(partials, outF);
}